// Round 14
// baseline (182.903 us; speedup 1.0000x reference)
//
#include <hip/hip_runtime.h>
#include <hip/hip_bf16.h>

#define NN 50000
#define NE 800000
#define KD 768
#define HIDD 128
#define NC 6
#define PADW 32
#define OVCAP 262144

typedef __attribute__((ext_vector_type(8))) short bf16x8;
typedef __attribute__((ext_vector_type(4))) float f32x4;

__device__ __forceinline__ ushort f2bf(float f) {
    union { float f; unsigned u; } v; v.f = f;
    unsigned u = v.u + 0x7FFF + ((v.u >> 16) & 1);   // round-to-nearest-even
    return (ushort)(u >> 16);
}
__device__ __forceinline__ float bf2f(ushort h) {
    union { unsigned u; float f; } v; v.u = ((unsigned)h) << 16;
    return v.f;
}
__device__ __forceinline__ void gll16(const void* g, void* l) {
    __builtin_amdgcn_global_load_lds((const __attribute__((address_space(1))) void*)g,
                                     (__attribute__((address_space(3))) void*)l, 16, 0, 0);
}
__device__ __forceinline__ float dinv_of(int c) {
    return rsqrtf((float)(c + 1));
}

// ---------------- weight prep granule (packed, gll-ready, swizzle baked in) ----------------

template <int KTOT>
__device__ __forceinline__ void pack_granule(const float* __restrict__ W,
                                             ushort* __restrict__ WTp, int gi) {
    const int KS = KTOT / 64;
    int ci = gi / (KS * 64);
    int rem = gi % (KS * 64);
    int ks = rem >> 6;
    int lane = rem & 63;
    int lr = lane >> 3;
    int lg = (lane & 7) ^ lr;
    int c = ci * 8 + lr;
    ushort tmp[8];
#pragma unroll
    for (int j = 0; j < 8; ++j)
        tmp[j] = f2bf(W[(size_t)(ks * 64 + lg * 8 + j) * HIDD + c]);
    *(bf16x8*)&WTp[(size_t)gi * 8] = *(bf16x8*)tmp;
}

// ---------------- K0: weight pack (blocks 0..55) + zero cnt (trailing, int4) ----------------

__global__ void pack_zero_kernel(int* __restrict__ cnt,
                                 const float* __restrict__ W1, const float* __restrict__ W2,
                                 ushort* __restrict__ WT1p, ushort* __restrict__ WT2p) {
    const int PB = 56;
    const int G1 = 16 * (KD / 64) * 64;     // 12288
    const int G2 = 16 * (HIDD / 64) * 64;   // 2048
    const int NZ4 = (NN + 64) / 4 + 1;
    int b = blockIdx.x;
    if (b < PB) {
        int gi = b * 256 + threadIdx.x;
        if (gi < G1) pack_granule<KD>(W1, WT1p, gi);
        else if (gi < G1 + G2) pack_granule<HIDD>(W2, WT2p, gi - G1);
    } else {
        int i = (b - PB) * 256 + threadIdx.x;
        if (i < NZ4) *(int4*)&cnt[i * 4] = make_int4(0, 0, 0, 0);
    }
}

// ---------------- K1: MFMA GEMM1 (blocks first, nt x-loads) + padded fill (nt ei-loads, nt stores) ----

__global__ __launch_bounds__(256) void gemm1_fill_kernel(
    const float* __restrict__ A, const ushort* __restrict__ WTp,
    ushort* __restrict__ out, int M,
    const int* __restrict__ ei, int* __restrict__ cnt,
    ushort* __restrict__ pad_col, int* __restrict__ ov_cnt, int2* __restrict__ ov) {
    const int GB = (NN + 63) / 64;   // 782
    __shared__ ushort As[64 * 64];
    __shared__ ushort Bs[128 * 64];
    if (blockIdx.x >= GB) {
        int base_e = (blockIdx.x - GB) * 512 + threadIdx.x;
#pragma unroll
        for (int rep = 0; rep < 2; ++rep) {
            int e = base_e + rep * 256;
            if (e < NE) {
                int sidx = __builtin_nontemporal_load(&ei[e]);
                int d = __builtin_nontemporal_load(&ei[NE + e]);
                sidx = min(max(sidx, 0), NN - 1);
                d = min(max(d, 0), NN - 1);
                int pos = atomicAdd(&cnt[d], 1);
                if (pos < PADW) {
                    __builtin_nontemporal_store((ushort)sidx, &pad_col[(size_t)d * PADW + pos]);
                } else {
                    int op = atomicAdd(ov_cnt, 1);
                    if (op < OVCAP) ov[op] = make_int2(d, sidx);
                }
            }
        }
        return;
    }
    const int KS = KD / 64;
    int t = threadIdx.x;
    int lane = t & 63;
    int wid = t >> 6;
    int wr = wid >> 1, wc = wid & 1;
    int row0 = blockIdx.x * 64;
    f32x4 acc[2][4] = {};

    for (int ks = 0; ks < KS; ++ks) {
        int k0 = ks * 64;
#pragma unroll
        for (int it = 0; it < 4; ++it) {
            int r = (t >> 4) + it * 16;
            int k4 = t & 15;
            int gr = min(row0 + r, M - 1);
            f32x4 v = __builtin_nontemporal_load(
                (const f32x4*)&A[(size_t)gr * KD + k0 + k4 * 4]);
            ushort4 w;
            w.x = f2bf(v[0]); w.y = f2bf(v[1]); w.z = f2bf(v[2]); w.w = f2bf(v[3]);
            int g = k4 >> 1, half = k4 & 1;
            *(ushort4*)&As[r * 64 + ((g ^ (r & 7)) * 8) + half * 4] = w;
        }
#pragma unroll
        for (int it = 0; it < 4; ++it) {
            int ci = wid * 4 + it;
            gll16(&WTp[(size_t)((ci * KS + ks) * 64 + lane) * 8], &Bs[ci * 512]);
        }
        __syncthreads();
#pragma unroll
        for (int h = 0; h < 2; ++h) {
            int q = h * 4 + (lane >> 4);
            bf16x8 a[2];
#pragma unroll
            for (int m = 0; m < 2; ++m) {
                int r = wr * 32 + m * 16 + (lane & 15);
                a[m] = *(const bf16x8*)&As[r * 64 + (q ^ (r & 7)) * 8];
            }
#pragma unroll
            for (int n = 0; n < 4; ++n) {
                int c = wc * 64 + n * 16 + (lane & 15);
                bf16x8 b = *(const bf16x8*)&Bs[c * 64 + (q ^ (c & 7)) * 8];
#pragma unroll
                for (int m = 0; m < 2; ++m)
                    acc[m][n] = __builtin_amdgcn_mfma_f32_16x16x32_bf16(a[m], b, acc[m][n], 0, 0, 0);
            }
        }
        __syncthreads();
    }
#pragma unroll
    for (int m = 0; m < 2; ++m) {
#pragma unroll
        for (int reg = 0; reg < 4; ++reg) {
            int row = row0 + wr * 32 + m * 16 + (lane >> 4) * 4 + reg;
            if (row < M) {
#pragma unroll
                for (int n = 0; n < 4; ++n) {
                    int colg = wc * 64 + n * 16 + (lane & 15);
                    out[(size_t)row * 128 + colg] = f2bf(acc[m][n][reg]);
                }
            }
        }
    }
}

// ---------------- gather tiers (ushort cols) ----------------

__device__ __forceinline__ void acc_edge(float& ax, float& ay, unsigned w) {
    ax += bf2f((ushort)(w & 0xffff));
    ay += bf2f((ushort)(w >> 16));
}

template <int U>
__device__ __forceinline__ int gather_tier_d(const ushort* __restrict__ hs,
                                             const ushort* __restrict__ cols,
                                             const int* __restrict__ cnt,
                                             int e, int e1, int l, float& ax, float& ay) {
    for (; e + U <= e1; e += U) {
        int j[U];
#pragma unroll
        for (int u = 0; u < U; ++u) j[u] = cols[e + u];
        unsigned w[U];
        float dj[U];
#pragma unroll
        for (int u = 0; u < U; ++u) {
            w[u] = *(const unsigned*)&hs[(size_t)j[u] * 128 + 2 * l];
            dj[u] = dinv_of(cnt[j[u]]);
        }
#pragma unroll
        for (int u = 0; u < U; ++u) {
            ax = fmaf(dj[u], bf2f((ushort)(w[u] & 0xffff)), ax);
            ay = fmaf(dj[u], bf2f((ushort)(w[u] >> 16)), ay);
        }
    }
    return e;
}

template <int U>
__device__ __forceinline__ int gather_tier(const ushort* __restrict__ hs,
                                           const ushort* __restrict__ cols,
                                           int e, int e1, int l, float& ax, float& ay) {
    for (; e + U <= e1; e += U) {
        unsigned w[U];
#pragma unroll
        for (int u = 0; u < U; ++u)
            w[u] = *(const unsigned*)&hs[(size_t)cols[e + u] * 128 + 2 * l];
#pragma unroll
        for (int u = 0; u < U; ++u) acc_edge(ax, ay, w[u]);
    }
    return e;
}

// ---------------- K2: fused agg1 + gemm2 ----------------

__global__ __launch_bounds__(256) void agg1_gemm2_kernel(
    const ushort* __restrict__ hs, const int* __restrict__ cnt,
    const ushort* __restrict__ pad_col, const float* __restrict__ bias,
    const int* __restrict__ ov_cnt, const int2* __restrict__ ov,
    const ushort* __restrict__ WT2p, ushort* __restrict__ outp) {
    __shared__ ushort h1s[16][136];
    int t = threadIdx.x;
    int wv = t >> 6;
    int l = t & 63;
    // ---- phase 1: gather 4 nodes per wave ----
    for (int k = 0; k < 4; ++k) {
        int r = wv * 4 + k;
        int i = blockIdx.x * 16 + r;
        int deg = cnt[i];
        float d = dinv_of(deg);
        unsigned v0 = *(const unsigned*)&hs[(size_t)i * 128 + 2 * l];
        float ax = d * bf2f((ushort)(v0 & 0xffff));
        float ay = d * bf2f((ushort)(v0 >> 16));
        int n = min(deg, PADW);
        const ushort* cols = pad_col + (size_t)i * PADW;
        int e = 0;
        e = gather_tier_d<16>(hs, cols, cnt, e, n, l, ax, ay);
        e = gather_tier_d<8>(hs, cols, cnt, e, n, l, ax, ay);
        e = gather_tier_d<4>(hs, cols, cnt, e, n, l, ax, ay);
        for (; e < n; ++e) {
            int j = cols[e];
            unsigned w = *(const unsigned*)&hs[(size_t)j * 128 + 2 * l];
            float dj = dinv_of(cnt[j]);
            ax = fmaf(dj, bf2f((ushort)(w & 0xffff)), ax);
            ay = fmaf(dj, bf2f((ushort)(w >> 16)), ay);
        }
        if (deg > PADW) {   // overflow rescue
            int oc = min(*ov_cnt, OVCAP);
            for (int kk = 0; kk < oc; ++kk) {
                int2 pr = ov[kk];
                if (pr.x == i) {
                    unsigned w = *(const unsigned*)&hs[(size_t)pr.y * 128 + 2 * l];
                    float dj = dinv_of(cnt[pr.y]);
                    ax = fmaf(dj, bf2f((ushort)(w & 0xffff)), ax);
                    ay = fmaf(dj, bf2f((ushort)(w >> 16)), ay);
                }
            }
        }
        float ox = fmaxf(fmaf(ax, d, bias[2 * l]), 0.f);
        float oy = fmaxf(fmaf(ay, d, bias[2 * l + 1]), 0.f);
        unsigned o = (unsigned)f2bf(ox) | ((unsigned)f2bf(oy) << 16);
        *(unsigned*)&h1s[r][2 * l] = o;
    }
    __syncthreads();
    // ---- phase 2: 16x128 @ 128x128 MFMA; wave wv owns cols [wv*32, wv*32+32) ----
    f32x4 acc2[2] = {};
#pragma unroll
    for (int ks = 0; ks < 4; ++ks) {
        int row = l & 15;
        bf16x8 a = *(const bf16x8*)&h1s[row][ks * 32 + (l >> 4) * 8];
#pragma unroll
        for (int n = 0; n < 2; ++n) {
            int c = wv * 32 + n * 16 + (l & 15);
            int ci = c >> 3, lr = c & 7;
            int ks64 = ks >> 1;
            int q64 = (ks & 1) * 4 + (l >> 4);
            const bf16x8 b = *(const bf16x8*)&WT2p[(size_t)((ci * 2 + ks64) * 64 + lr * 8 + (q64 ^ lr)) * 8];
            acc2[n] = __builtin_amdgcn_mfma_f32_16x16x32_bf16(a, b, acc2[n], 0, 0, 0);
        }
    }
#pragma unroll
    for (int n = 0; n < 2; ++n) {
        int c = wv * 32 + n * 16 + (l & 15);
#pragma unroll
        for (int reg = 0; reg < 4; ++reg) {
            int r = (l >> 4) * 4 + reg;
            int node = blockIdx.x * 16 + r;
            float dd = dinv_of(cnt[node]);
            outp[(size_t)node * 128 + c] = f2bf(acc2[n][reg] * dd);
        }
    }
}

// ---------------- K3: agg2 + heads ----------------

__global__ void agg2_heads_kernel(const ushort* __restrict__ hs, const int* __restrict__ cnt,
                                  const ushort* __restrict__ pad_col,
                                  const float* __restrict__ bias,
                                  const int* __restrict__ ov_cnt, const int2* __restrict__ ov,
                                  const float* __restrict__ Wi, const float* __restrict__ bi,
                                  const float* __restrict__ Wl, const float* __restrict__ bl,
                                  float* __restrict__ out) {
    int wv = threadIdx.x >> 6;
    int l = threadIdx.x & 63;
    int i = blockIdx.x * 4 + wv;
    unsigned v0 = *(const unsigned*)&hs[(size_t)i * 128 + 2 * l];
    float ax = bf2f((ushort)(v0 & 0xffff));
    float ay = bf2f((ushort)(v0 >> 16));
    int deg = cnt[i];
    int n = min(deg, PADW);
    const ushort* cols = pad_col + (size_t)i * PADW;
    int e = 0;
    e = gather_tier<16>(hs, cols, e, n, l, ax, ay);
    e = gather_tier<8>(hs, cols, e, n, l, ax, ay);
    e = gather_tier<4>(hs, cols, e, n, l, ax, ay);
    for (; e < n; ++e)
        acc_edge(ax, ay, *(const unsigned*)&hs[(size_t)cols[e] * 128 + 2 * l]);
    if (deg > PADW) {
        int oc = min(*ov_cnt, OVCAP);
        for (int k = 0; k < oc; ++k) {
            int2 pr = ov[k];
            if (pr.x == i)
                acc_edge(ax, ay, *(const unsigned*)&hs[(size_t)pr.y * 128 + 2 * l]);
        }
    }
    float d = dinv_of(deg);
    float ox = fmaxf(fmaf(ax, d, bias[2 * l]), 0.f);
    float oy = fmaxf(fmaf(ay, d, bias[2 * l + 1]), 0.f);

    float4 u0 = *(const float4*)&Wi[l * 12];
    float4 u1 = *(const float4*)&Wi[l * 12 + 4];
    float4 u2 = *(const float4*)&Wi[l * 12 + 8];
    float pi[6];
    pi[0] = ox * u0.x + oy * u1.z;
    pi[1] = ox * u0.y + oy * u1.w;
    pi[2] = ox * u0.z + oy * u2.x;
    pi[3] = ox * u0.w + oy * u2.y;
    pi[4] = ox * u1.x + oy * u2.z;
    pi[5] = ox * u1.y + oy * u2.w;
    u0 = *(const float4*)&Wl[l * 12];
    u1 = *(const float4*)&Wl[l * 12 + 4];
    u2 = *(const float4*)&Wl[l * 12 + 8];
    float pl[6];
    pl[0] = ox * u0.x + oy * u1.z;
    pl[1] = ox * u0.y + oy * u1.w;
    pl[2] = ox * u0.z + oy * u2.x;
    pl[3] = ox * u0.w + oy * u2.y;
    pl[4] = ox * u1.x + oy * u2.z;
    pl[5] = ox * u1.y + oy * u2.w;
#pragma unroll
    for (int off = 1; off < 64; off <<= 1) {
#pragma unroll
        for (int c = 0; c < 6; ++c) {
            pi[c] += __shfl_xor(pi[c], off);
            pl[c] += __shfl_xor(pl[c], off);
        }
    }
#pragma unroll
    for (int c = 0; c < 6; ++c) {
        pi[c] += bi[c];
        pl[c] += bl[c];
    }
    float mi = fmaxf(fmaxf(fmaxf(pi[0], pi[1]), fmaxf(pi[2], pi[3])), fmaxf(pi[4], pi[5]));
    float ml = fmaxf(fmaxf(fmaxf(pl[0], pl[1]), fmaxf(pl[2], pl[3])), fmaxf(pl[4], pl[5]));
    float si = 0.f, sl = 0.f;
#pragma unroll
    for (int c = 0; c < 6; ++c) {
        si += expf(pi[c] - mi);
        sl += expf(pl[c] - ml);
    }
    float lsi = mi + logf(si), lsl = ml + logf(sl);
#pragma unroll
    for (int c = 0; c < 6; ++c) {
        if (l == c)     out[(size_t)i * NC + c] = pi[c] - lsi;
        if (l == 6 + c) out[(size_t)NN * NC + (size_t)i * NC + c] = pl[c] - lsl;
    }
}

extern "C" void kernel_launch(void* const* d_in, const int* in_sizes, int n_in,
                              void* d_out, int out_size, void* d_ws, size_t ws_size,
                              hipStream_t stream) {
    const float* x  = (const float*)d_in[0];
    const int*   ei = (const int*)d_in[1];
    const float* W1 = (const float*)d_in[2];
    const float* b1 = (const float*)d_in[3];
    const float* W2 = (const float*)d_in[4];
    const float* b2 = (const float*)d_in[5];
    const float* Wi = (const float*)d_in[6];
    const float* bi = (const float*)d_in[7];
    const float* Wl = (const float*)d_in[8];
    const float* bl = (const float*)d_in[9];
    float* out = (float*)d_out;

    uint8_t* p = (uint8_t*)d_ws;
    auto alloc = [&](size_t bytes) {
        void* r = (void*)p;
        p += (bytes + 255) / 256 * 256;
        return r;
    };
    int* cnt        = (int*)alloc((NN + 68) * sizeof(int));   // cnt + ov_cnt at [NN]
    ushort* pad_col = (ushort*)alloc((size_t)NN * PADW * sizeof(ushort));
    int2* ov        = (int2*)alloc((size_t)OVCAP * sizeof(int2));
    ushort* WT1p    = (ushort*)alloc((size_t)KD * HIDD * sizeof(ushort));
    ushort* WT2p    = (ushort*)alloc((size_t)HIDD * HIDD * sizeof(ushort));
    ushort* bufA    = (ushort*)alloc((size_t)NN * HIDD * sizeof(ushort));  // hs1
    ushort* bufC    = (ushort*)alloc((size_t)NN * HIDD * sizeof(ushort));  // hs2
    int* ov_cnt = cnt + NN;

    const int FB = (NE + 511) / 512;       // 1563 fill blocks
    const int PB = 56;                     // pack blocks
    const int NZ4 = (NN + 64) / 4 + 1;
    const int ZB = (NZ4 + 255) / 256;      // 49 zero blocks
    const int GB = (NN + 63) / 64;         // 782 gemm blocks

    // K0: pack weights + zero cnt/ov_cnt
    pack_zero_kernel<<<PB + ZB, 256, 0, stream>>>(cnt, W1, W2, WT1p, WT2p);
    // K1: gemm1 (long blocks first, nt x) || single-pass padded fill (nt)
    gemm1_fill_kernel<<<GB + FB, 256, 0, stream>>>(x, WT1p, bufA, NN,
                                                   ei, cnt, pad_col, ov_cnt, ov);
    // K2: fused agg1 + gemm2 -> hs2
    agg1_gemm2_kernel<<<NN / 16, 256, 0, stream>>>(bufA, cnt, pad_col, b1, ov_cnt, ov,
                                                   WT2p, bufC);
    // K3: agg2 + heads
    agg2_heads_kernel<<<NN / 4, 256, 0, stream>>>(bufC, cnt, pad_col, b2, ov_cnt, ov,
                                                  Wi, bi, Wl, bl, out);
}

// Round 15
// 175.698 us; speedup vs baseline: 1.0410x; 1.0410x over previous
//
#include <hip/hip_runtime.h>
#include <hip/hip_bf16.h>

#define NN 50000
#define NE 800000
#define KD 768
#define HIDD 128
#define NC 6
#define SLOTS 30
#define ROWU 32
#define OVCAP 262144

typedef __attribute__((ext_vector_type(8))) short bf16x8;
typedef __attribute__((ext_vector_type(4))) float f32x4;

__device__ __forceinline__ ushort f2bf(float f) {
    union { float f; unsigned u; } v; v.f = f;
    unsigned u = v.u + 0x7FFF + ((v.u >> 16) & 1);   // round-to-nearest-even
    return (ushort)(u >> 16);
}
__device__ __forceinline__ float bf2f(ushort h) {
    union { unsigned u; float f; } v; v.u = ((unsigned)h) << 16;
    return v.f;
}
__device__ __forceinline__ void gll16(const void* g, void* l) {
    __builtin_amdgcn_global_load_lds((const __attribute__((address_space(1))) void*)g,
                                     (__attribute__((address_space(3))) void*)l, 16, 0, 0);
}
__device__ __forceinline__ float dinv_of(int c) {
    return rsqrtf((float)(c + 1));
}

// ---------------- weight prep granule (packed, gll-ready, swizzle baked in) ----------------

template <int KTOT>
__device__ __forceinline__ void pack_granule(const float* __restrict__ W,
                                             ushort* __restrict__ WTp, int gi) {
    const int KS = KTOT / 64;
    int ci = gi / (KS * 64);
    int rem = gi % (KS * 64);
    int ks = rem >> 6;
    int lane = rem & 63;
    int lr = lane >> 3;
    int lg = (lane & 7) ^ lr;
    int c = ci * 8 + lr;
    ushort tmp[8];
#pragma unroll
    for (int j = 0; j < 8; ++j)
        tmp[j] = f2bf(W[(size_t)(ks * 64 + lg * 8 + j) * HIDD + c]);
    *(bf16x8*)&WTp[(size_t)gi * 8] = *(bf16x8*)tmp;
}

// ---------------- K0: weight pack (blocks 0..55) + zero pad rows (trailing, int4) ----------------

__global__ void pack_zero_kernel(int* __restrict__ padz,
                                 const float* __restrict__ W1, const float* __restrict__ W2,
                                 ushort* __restrict__ WT1p, ushort* __restrict__ WT2p) {
    const int PB = 56;
    const int G1 = 16 * (KD / 64) * 64;     // 12288
    const int G2 = 16 * (HIDD / 64) * 64;   // 2048
    const int NZ4 = (NN * (ROWU / 2) + 16 + 3) / 4;   // pad rows + ov_cnt region
    int b = blockIdx.x;
    if (b < PB) {
        int gi = b * 256 + threadIdx.x;
        if (gi < G1) pack_granule<KD>(W1, WT1p, gi);
        else if (gi < G1 + G2) pack_granule<HIDD>(W2, WT2p, gi - G1);
    } else {
        int i = (b - PB) * 256 + threadIdx.x;
        if (i < NZ4) *(int4*)&padz[i * 4] = make_int4(0, 0, 0, 0);
    }
}

// ---------------- K1: MFMA GEMM1 (blocks first) + padded fill (counter embedded in row) ----------------
// fill: per edge ONE random 64B line: atomicAdd on row head + store into same line.

__global__ __launch_bounds__(256) void gemm1_fill_kernel(
    const float* __restrict__ A, const ushort* __restrict__ WTp,
    ushort* __restrict__ out, int M,
    const int* __restrict__ ei, ushort* __restrict__ pad_col,
    int* __restrict__ ov_cnt, int2* __restrict__ ov) {
    const int GB = (NN + 63) / 64;   // 782
    __shared__ ushort As[64 * 64];
    __shared__ ushort Bs[128 * 64];
    if (blockIdx.x >= GB) {
        int base_e = (blockIdx.x - GB) * 512 + threadIdx.x;
#pragma unroll
        for (int rep = 0; rep < 2; ++rep) {
            int e = base_e + rep * 256;
            if (e < NE) {
                int sidx = ei[e];
                int d = ei[NE + e];
                sidx = min(max(sidx, 0), NN - 1);
                d = min(max(d, 0), NN - 1);
                int pos = atomicAdd((int*)&pad_col[(size_t)d * ROWU], 1);
                if (pos < SLOTS) {
                    pad_col[(size_t)d * ROWU + 2 + pos] = (ushort)sidx;
                } else {
                    int op = atomicAdd(ov_cnt, 1);
                    if (op < OVCAP) ov[op] = make_int2(d, sidx);
                }
            }
        }
        return;
    }
    const int KS = KD / 64;
    int t = threadIdx.x;
    int lane = t & 63;
    int wid = t >> 6;
    int wr = wid >> 1, wc = wid & 1;
    int row0 = blockIdx.x * 64;
    f32x4 acc[2][4] = {};

    for (int ks = 0; ks < KS; ++ks) {
        int k0 = ks * 64;
#pragma unroll
        for (int it = 0; it < 4; ++it) {
            int r = (t >> 4) + it * 16;
            int k4 = t & 15;
            int gr = min(row0 + r, M - 1);
            float4 v = *(const float4*)&A[(size_t)gr * KD + k0 + k4 * 4];
            ushort4 w;
            w.x = f2bf(v.x); w.y = f2bf(v.y); w.z = f2bf(v.z); w.w = f2bf(v.w);
            int g = k4 >> 1, half = k4 & 1;
            *(ushort4*)&As[r * 64 + ((g ^ (r & 7)) * 8) + half * 4] = w;
        }
#pragma unroll
        for (int it = 0; it < 4; ++it) {
            int ci = wid * 4 + it;
            gll16(&WTp[(size_t)((ci * KS + ks) * 64 + lane) * 8], &Bs[ci * 512]);
        }
        __syncthreads();
#pragma unroll
        for (int h = 0; h < 2; ++h) {
            int q = h * 4 + (lane >> 4);
            bf16x8 a[2];
#pragma unroll
            for (int m = 0; m < 2; ++m) {
                int r = wr * 32 + m * 16 + (lane & 15);
                a[m] = *(const bf16x8*)&As[r * 64 + (q ^ (r & 7)) * 8];
            }
#pragma unroll
            for (int n = 0; n < 4; ++n) {
                int c = wc * 64 + n * 16 + (lane & 15);
                bf16x8 b = *(const bf16x8*)&Bs[c * 64 + (q ^ (c & 7)) * 8];
#pragma unroll
                for (int m = 0; m < 2; ++m)
                    acc[m][n] = __builtin_amdgcn_mfma_f32_16x16x32_bf16(a[m], b, acc[m][n], 0, 0, 0);
            }
        }
        __syncthreads();
    }
#pragma unroll
    for (int m = 0; m < 2; ++m) {
#pragma unroll
        for (int reg = 0; reg < 4; ++reg) {
            int row = row0 + wr * 32 + m * 16 + (lane >> 4) * 4 + reg;
            if (row < M) {
#pragma unroll
                for (int n = 0; n < 4; ++n) {
                    int colg = wc * 64 + n * 16 + (lane & 15);
                    out[(size_t)row * 128 + colg] = f2bf(acc[m][n][reg]);
                }
            }
        }
    }
}

// ---------------- K1b: extract degrees to compact array (coalesced) ----------------

__global__ void cnt_copy_kernel(const ushort* __restrict__ pad_col, int* __restrict__ cntc) {
    int i = blockIdx.x * blockDim.x + threadIdx.x;
    if (i < NN) cntc[i] = *(const int*)&pad_col[(size_t)i * ROWU];
}

// ---------------- gather tiers (ushort cols) ----------------

__device__ __forceinline__ void acc_edge(float& ax, float& ay, unsigned w) {
    ax += bf2f((ushort)(w & 0xffff));
    ay += bf2f((ushort)(w >> 16));
}

template <int U>
__device__ __forceinline__ int gather_tier_d(const ushort* __restrict__ hs,
                                             const ushort* __restrict__ cols,
                                             const int* __restrict__ cnt,
                                             int e, int e1, int l, float& ax, float& ay) {
    for (; e + U <= e1; e += U) {
        int j[U];
#pragma unroll
        for (int u = 0; u < U; ++u) j[u] = cols[e + u];
        unsigned w[U];
        float dj[U];
#pragma unroll
        for (int u = 0; u < U; ++u) {
            w[u] = *(const unsigned*)&hs[(size_t)j[u] * 128 + 2 * l];
            dj[u] = dinv_of(cnt[j[u]]);
        }
#pragma unroll
        for (int u = 0; u < U; ++u) {
            ax = fmaf(dj[u], bf2f((ushort)(w[u] & 0xffff)), ax);
            ay = fmaf(dj[u], bf2f((ushort)(w[u] >> 16)), ay);
        }
    }
    return e;
}

template <int U>
__device__ __forceinline__ int gather_tier(const ushort* __restrict__ hs,
                                           const ushort* __restrict__ cols,
                                           int e, int e1, int l, float& ax, float& ay) {
    for (; e + U <= e1; e += U) {
        unsigned w[U];
#pragma unroll
        for (int u = 0; u < U; ++u)
            w[u] = *(const unsigned*)&hs[(size_t)cols[e + u] * 128 + 2 * l];
#pragma unroll
        for (int u = 0; u < U; ++u) acc_edge(ax, ay, w[u]);
    }
    return e;
}

// ---------------- K2: fused agg1 + gemm2 ----------------

__global__ __launch_bounds__(256) void agg1_gemm2_kernel(
    const ushort* __restrict__ hs, const int* __restrict__ cnt,
    const ushort* __restrict__ pad_col, const float* __restrict__ bias,
    const int* __restrict__ ov_cnt, const int2* __restrict__ ov,
    const ushort* __restrict__ WT2p, ushort* __restrict__ outp) {
    __shared__ ushort h1s[16][136];
    int t = threadIdx.x;
    int wv = t >> 6;
    int l = t & 63;
    // ---- phase 1: gather 4 nodes per wave ----
    for (int k = 0; k < 4; ++k) {
        int r = wv * 4 + k;
        int i = blockIdx.x * 16 + r;
        int deg = cnt[i];
        float d = dinv_of(deg);
        unsigned v0 = *(const unsigned*)&hs[(size_t)i * 128 + 2 * l];
        float ax = d * bf2f((ushort)(v0 & 0xffff));
        float ay = d * bf2f((ushort)(v0 >> 16));
        int n = min(deg, SLOTS);
        const ushort* cols = pad_col + (size_t)i * ROWU + 2;
        int e = 0;
        e = gather_tier_d<16>(hs, cols, cnt, e, n, l, ax, ay);
        e = gather_tier_d<8>(hs, cols, cnt, e, n, l, ax, ay);
        e = gather_tier_d<4>(hs, cols, cnt, e, n, l, ax, ay);
        for (; e < n; ++e) {
            int j = cols[e];
            unsigned w = *(const unsigned*)&hs[(size_t)j * 128 + 2 * l];
            float dj = dinv_of(cnt[j]);
            ax = fmaf(dj, bf2f((ushort)(w & 0xffff)), ax);
            ay = fmaf(dj, bf2f((ushort)(w >> 16)), ay);
        }
        if (deg > SLOTS) {   // overflow rescue (~10 nodes worst case)
            int oc = min(*ov_cnt, OVCAP);
            for (int kk = 0; kk < oc; ++kk) {
                int2 pr = ov[kk];
                if (pr.x == i) {
                    unsigned w = *(const unsigned*)&hs[(size_t)pr.y * 128 + 2 * l];
                    float dj = dinv_of(cnt[pr.y]);
                    ax = fmaf(dj, bf2f((ushort)(w & 0xffff)), ax);
                    ay = fmaf(dj, bf2f((ushort)(w >> 16)), ay);
                }
            }
        }
        float ox = fmaxf(fmaf(ax, d, bias[2 * l]), 0.f);
        float oy = fmaxf(fmaf(ay, d, bias[2 * l + 1]), 0.f);
        unsigned o = (unsigned)f2bf(ox) | ((unsigned)f2bf(oy) << 16);
        *(unsigned*)&h1s[r][2 * l] = o;
    }
    __syncthreads();
    // ---- phase 2: 16x128 @ 128x128 MFMA; wave wv owns cols [wv*32, wv*32+32) ----
    f32x4 acc2[2] = {};
#pragma unroll
    for (int ks = 0; ks < 4; ++ks) {
        int row = l & 15;
        bf16x8 a = *(const bf16x8*)&h1s[row][ks * 32 + (l >> 4) * 8];
#pragma unroll
        for (int n = 0; n < 2; ++n) {
            int c = wv * 32 + n * 16 + (l & 15);
            int ci = c >> 3, lr = c & 7;
            int ks64 = ks >> 1;
            int q64 = (ks & 1) * 4 + (l >> 4);
            const bf16x8 b = *(const bf16x8*)&WT2p[(size_t)((ci * 2 + ks64) * 64 + lr * 8 + (q64 ^ lr)) * 8];
            acc2[n] = __builtin_amdgcn_mfma_f32_16x16x32_bf16(a, b, acc2[n], 0, 0, 0);
        }
    }
#pragma unroll
    for (int n = 0; n < 2; ++n) {
        int c = wv * 32 + n * 16 + (l & 15);
#pragma unroll
        for (int reg = 0; reg < 4; ++reg) {
            int r = (l >> 4) * 4 + reg;
            int node = blockIdx.x * 16 + r;
            float dd = dinv_of(cnt[node]);
            outp[(size_t)node * 128 + c] = f2bf(acc2[n][reg] * dd);
        }
    }
}

// ---------------- K3: agg2 + heads ----------------

__global__ void agg2_heads_kernel(const ushort* __restrict__ hs, const int* __restrict__ cnt,
                                  const ushort* __restrict__ pad_col,
                                  const float* __restrict__ bias,
                                  const int* __restrict__ ov_cnt, const int2* __restrict__ ov,
                                  const float* __restrict__ Wi, const float* __restrict__ bi,
                                  const float* __restrict__ Wl, const float* __restrict__ bl,
                                  float* __restrict__ out) {
    int wv = threadIdx.x >> 6;
    int l = threadIdx.x & 63;
    int i = blockIdx.x * 4 + wv;
    unsigned v0 = *(const unsigned*)&hs[(size_t)i * 128 + 2 * l];
    float ax = bf2f((ushort)(v0 & 0xffff));
    float ay = bf2f((ushort)(v0 >> 16));
    int deg = cnt[i];
    int n = min(deg, SLOTS);
    const ushort* cols = pad_col + (size_t)i * ROWU + 2;
    int e = 0;
    e = gather_tier<16>(hs, cols, e, n, l, ax, ay);
    e = gather_tier<8>(hs, cols, e, n, l, ax, ay);
    e = gather_tier<4>(hs, cols, e, n, l, ax, ay);
    for (; e < n; ++e)
        acc_edge(ax, ay, *(const unsigned*)&hs[(size_t)cols[e] * 128 + 2 * l]);
    if (deg > SLOTS) {
        int oc = min(*ov_cnt, OVCAP);
        for (int k = 0; k < oc; ++k) {
            int2 pr = ov[k];
            if (pr.x == i)
                acc_edge(ax, ay, *(const unsigned*)&hs[(size_t)pr.y * 128 + 2 * l]);
        }
    }
    float d = dinv_of(deg);
    float ox = fmaxf(fmaf(ax, d, bias[2 * l]), 0.f);
    float oy = fmaxf(fmaf(ay, d, bias[2 * l + 1]), 0.f);

    float4 u0 = *(const float4*)&Wi[l * 12];
    float4 u1 = *(const float4*)&Wi[l * 12 + 4];
    float4 u2 = *(const float4*)&Wi[l * 12 + 8];
    float pi[6];
    pi[0] = ox * u0.x + oy * u1.z;
    pi[1] = ox * u0.y + oy * u1.w;
    pi[2] = ox * u0.z + oy * u2.x;
    pi[3] = ox * u0.w + oy * u2.y;
    pi[4] = ox * u1.x + oy * u2.z;
    pi[5] = ox * u1.y + oy * u2.w;
    u0 = *(const float4*)&Wl[l * 12];
    u1 = *(const float4*)&Wl[l * 12 + 4];
    u2 = *(const float4*)&Wl[l * 12 + 8];
    float pl[6];
    pl[0] = ox * u0.x + oy * u1.z;
    pl[1] = ox * u0.y + oy * u1.w;
    pl[2] = ox * u0.z + oy * u2.x;
    pl[3] = ox * u0.w + oy * u2.y;
    pl[4] = ox * u1.x + oy * u2.z;
    pl[5] = ox * u1.y + oy * u2.w;
#pragma unroll
    for (int off = 1; off < 64; off <<= 1) {
#pragma unroll
        for (int c = 0; c < 6; ++c) {
            pi[c] += __shfl_xor(pi[c], off);
            pl[c] += __shfl_xor(pl[c], off);
        }
    }
#pragma unroll
    for (int c = 0; c < 6; ++c) {
        pi[c] += bi[c];
        pl[c] += bl[c];
    }
    float mi = fmaxf(fmaxf(fmaxf(pi[0], pi[1]), fmaxf(pi[2], pi[3])), fmaxf(pi[4], pi[5]));
    float ml = fmaxf(fmaxf(fmaxf(pl[0], pl[1]), fmaxf(pl[2], pl[3])), fmaxf(pl[4], pl[5]));
    float si = 0.f, sl = 0.f;
#pragma unroll
    for (int c = 0; c < 6; ++c) {
        si += expf(pi[c] - mi);
        sl += expf(pl[c] - ml);
    }
    float lsi = mi + logf(si), lsl = ml + logf(sl);
#pragma unroll
    for (int c = 0; c < 6; ++c) {
        if (l == c)     out[(size_t)i * NC + c] = pi[c] - lsi;
        if (l == 6 + c) out[(size_t)NN * NC + (size_t)i * NC + c] = pl[c] - lsl;
    }
}

extern "C" void kernel_launch(void* const* d_in, const int* in_sizes, int n_in,
                              void* d_out, int out_size, void* d_ws, size_t ws_size,
                              hipStream_t stream) {
    const float* x  = (const float*)d_in[0];
    const int*   ei = (const int*)d_in[1];
    const float* W1 = (const float*)d_in[2];
    const float* b1 = (const float*)d_in[3];
    const float* W2 = (const float*)d_in[4];
    const float* b2 = (const float*)d_in[5];
    const float* Wi = (const float*)d_in[6];
    const float* bi = (const float*)d_in[7];
    const float* Wl = (const float*)d_in[8];
    const float* bl = (const float*)d_in[9];
    float* out = (float*)d_out;

    uint8_t* p = (uint8_t*)d_ws;
    auto alloc = [&](size_t bytes) {
        void* r = (void*)p;
        p += (bytes + 255) / 256 * 256;
        return r;
    };
    ushort* pad_col = (ushort*)alloc(((size_t)NN * ROWU + 64) * sizeof(ushort)); // rows + ov_cnt
    int2* ov        = (int2*)alloc((size_t)OVCAP * sizeof(int2));
    int* cntc       = (int*)alloc(NN * sizeof(int));
    ushort* WT1p    = (ushort*)alloc((size_t)KD * HIDD * sizeof(ushort));
    ushort* WT2p    = (ushort*)alloc((size_t)HIDD * HIDD * sizeof(ushort));
    ushort* bufA    = (ushort*)alloc((size_t)NN * HIDD * sizeof(ushort));  // hs1
    ushort* bufC    = (ushort*)alloc((size_t)NN * HIDD * sizeof(ushort));  // hs2
    int* ov_cnt = (int*)(pad_col + (size_t)NN * ROWU);

    const int FB = (NE + 511) / 512;       // 1563 fill blocks
    const int PB = 56;                     // pack blocks
    const int NZ4 = (NN * (ROWU / 2) + 16 + 3) / 4;
    const int ZB = (NZ4 + 255) / 256;      // 782 zero blocks (int4)
    const int GB = (NN + 63) / 64;         // 782 gemm blocks

    // K0: pack weights + zero pad rows (counters) + ov_cnt
    pack_zero_kernel<<<PB + ZB, 256, 0, stream>>>((int*)pad_col, W1, W2, WT1p, WT2p);
    // K1: gemm1 (long blocks first) || single-pass fill (1 random line per edge)
    gemm1_fill_kernel<<<GB + FB, 256, 0, stream>>>(x, WT1p, bufA, NN,
                                                   ei, pad_col, ov_cnt, ov);
    // K1b: extract degrees (coalesced)
    cnt_copy_kernel<<<(NN + 255) / 256, 256, 0, stream>>>(pad_col, cntc);
    // K2: fused agg1 + gemm2 -> hs2
    agg1_gemm2_kernel<<<NN / 16, 256, 0, stream>>>(bufA, cntc, pad_col, b1, ov_cnt, ov,
                                                   WT2p, bufC);
    // K3: agg2 + heads
    agg2_heads_kernel<<<NN / 4, 256, 0, stream>>>(bufC, cntc, pad_col, b2, ov_cnt, ov,
                                                  Wi, bi, Wl, bl, out);
}

// Round 16
// 168.071 us; speedup vs baseline: 1.0883x; 1.0454x over previous
//
#include <hip/hip_runtime.h>
#include <hip/hip_bf16.h>

#define NN 50000
#define NE 800000
#define KD 768
#define HIDD 128
#define NC 6
#define PADW 32
#define OVCAP 262144

typedef __attribute__((ext_vector_type(8))) short bf16x8;
typedef __attribute__((ext_vector_type(4))) float f32x4;

__device__ __forceinline__ ushort f2bf(float f) {
    union { float f; unsigned u; } v; v.f = f;
    unsigned u = v.u + 0x7FFF + ((v.u >> 16) & 1);   // round-to-nearest-even
    return (ushort)(u >> 16);
}
__device__ __forceinline__ ushort f2bf_hw(float f) {
    __hip_bfloat16 h = __float2bfloat16(f);          // HW RNE — same bits as f2bf
    return *(ushort*)&h;
}
__device__ __forceinline__ float bf2f(ushort h) {
    union { unsigned u; float f; } v; v.u = ((unsigned)h) << 16;
    return v.f;
}
__device__ __forceinline__ void gll16(const void* g, void* l) {
    __builtin_amdgcn_global_load_lds((const __attribute__((address_space(1))) void*)g,
                                     (__attribute__((address_space(3))) void*)l, 16, 0, 0);
}
__device__ __forceinline__ float dinv_of(int c) {
    return rsqrtf((float)(c + 1));
}

// ---------------- weight prep granule (packed, gll-ready, swizzle baked in) ----------------

template <int KTOT>
__device__ __forceinline__ void pack_granule(const float* __restrict__ W,
                                             ushort* __restrict__ WTp, int gi) {
    const int KS = KTOT / 64;
    int ci = gi / (KS * 64);
    int rem = gi % (KS * 64);
    int ks = rem >> 6;
    int lane = rem & 63;
    int lr = lane >> 3;
    int lg = (lane & 7) ^ lr;
    int c = ci * 8 + lr;
    ushort tmp[8];
#pragma unroll
    for (int j = 0; j < 8; ++j)
        tmp[j] = f2bf(W[(size_t)(ks * 64 + lg * 8 + j) * HIDD + c]);
    *(bf16x8*)&WTp[(size_t)gi * 8] = *(bf16x8*)tmp;
}

// ---------------- K0: weight pack (blocks 0..55) + zero cnt (trailing, int4) ----------------

__global__ void pack_zero_kernel(int* __restrict__ cnt,
                                 const float* __restrict__ W1, const float* __restrict__ W2,
                                 ushort* __restrict__ WT1p, ushort* __restrict__ WT2p) {
    const int PB = 56;
    const int G1 = 16 * (KD / 64) * 64;     // 12288
    const int G2 = 16 * (HIDD / 64) * 64;   // 2048
    const int NZ4 = (NN + 64) / 4 + 1;
    int b = blockIdx.x;
    if (b < PB) {
        int gi = b * 256 + threadIdx.x;
        if (gi < G1) pack_granule<KD>(W1, WT1p, gi);
        else if (gi < G1 + G2) pack_granule<HIDD>(W2, WT2p, gi - G1);
    } else {
        int i = (b - PB) * 256 + threadIdx.x;
        if (i < NZ4) *(int4*)&cnt[i * 4] = make_int4(0, 0, 0, 0);
    }
}

// ---------------- K1: MFMA GEMM1 (blocks first) + padded-CSR fill (trailing, ushort cols) ----------------

__global__ __launch_bounds__(256) void gemm1_fill_kernel(
    const float* __restrict__ A, const ushort* __restrict__ WTp,
    ushort* __restrict__ out, int M,
    const int* __restrict__ ei, int* __restrict__ cnt,
    ushort* __restrict__ pad_col, int* __restrict__ ov_cnt, int2* __restrict__ ov) {
    const int GB = (NN + 63) / 64;   // 782
    __shared__ ushort As[64 * 64];
    __shared__ ushort Bs[128 * 64];
    if (blockIdx.x >= GB) {
        int base_e = (blockIdx.x - GB) * 512 + threadIdx.x;
#pragma unroll
        for (int rep = 0; rep < 2; ++rep) {
            int e = base_e + rep * 256;
            if (e < NE) {
                int sidx = ei[e];
                int d = ei[NE + e];
                sidx = min(max(sidx, 0), NN - 1);
                d = min(max(d, 0), NN - 1);
                int pos = atomicAdd(&cnt[d], 1);
                if (pos < PADW) {
                    pad_col[(size_t)d * PADW + pos] = (ushort)sidx;
                } else {
                    int op = atomicAdd(ov_cnt, 1);
                    if (op < OVCAP) ov[op] = make_int2(d, sidx);
                }
            }
        }
        return;
    }
    const int KS = KD / 64;
    int t = threadIdx.x;
    int lane = t & 63;
    int wid = t >> 6;
    int wr = wid >> 1, wc = wid & 1;
    int row0 = blockIdx.x * 64;
    f32x4 acc[2][4] = {};

    for (int ks = 0; ks < KS; ++ks) {
        int k0 = ks * 64;
#pragma unroll
        for (int it = 0; it < 4; ++it) {
            int r = (t >> 4) + it * 16;
            int k4 = t & 15;
            int gr = min(row0 + r, M - 1);
            float4 v = *(const float4*)&A[(size_t)gr * KD + k0 + k4 * 4];
            ushort4 w;
            w.x = f2bf_hw(v.x); w.y = f2bf_hw(v.y); w.z = f2bf_hw(v.z); w.w = f2bf_hw(v.w);
            int g = k4 >> 1, half = k4 & 1;
            *(ushort4*)&As[r * 64 + ((g ^ (r & 7)) * 8) + half * 4] = w;
        }
#pragma unroll
        for (int it = 0; it < 4; ++it) {
            int ci = wid * 4 + it;
            gll16(&WTp[(size_t)((ci * KS + ks) * 64 + lane) * 8], &Bs[ci * 512]);
        }
        __syncthreads();
#pragma unroll
        for (int h = 0; h < 2; ++h) {
            int q = h * 4 + (lane >> 4);
            bf16x8 a[2];
#pragma unroll
            for (int m = 0; m < 2; ++m) {
                int r = wr * 32 + m * 16 + (lane & 15);
                a[m] = *(const bf16x8*)&As[r * 64 + (q ^ (r & 7)) * 8];
            }
#pragma unroll
            for (int n = 0; n < 4; ++n) {
                int c = wc * 64 + n * 16 + (lane & 15);
                bf16x8 b = *(const bf16x8*)&Bs[c * 64 + (q ^ (c & 7)) * 8];
#pragma unroll
                for (int m = 0; m < 2; ++m)
                    acc[m][n] = __builtin_amdgcn_mfma_f32_16x16x32_bf16(a[m], b, acc[m][n], 0, 0, 0);
            }
        }
        __syncthreads();
    }
#pragma unroll
    for (int m = 0; m < 2; ++m) {
#pragma unroll
        for (int reg = 0; reg < 4; ++reg) {
            int row = row0 + wr * 32 + m * 16 + (lane >> 4) * 4 + reg;
            if (row < M) {
#pragma unroll
                for (int n = 0; n < 4; ++n) {
                    int colg = wc * 64 + n * 16 + (lane & 15);
                    out[(size_t)row * 128 + colg] = f2bf(acc[m][n][reg]);
                }
            }
        }
    }
}

// ---------------- gather tiers (ushort cols) ----------------

__device__ __forceinline__ void acc_edge(float& ax, float& ay, unsigned w) {
    ax += bf2f((ushort)(w & 0xffff));
    ay += bf2f((ushort)(w >> 16));
}

template <int U>
__device__ __forceinline__ int gather_tier_d(const ushort* __restrict__ hs,
                                             const ushort* __restrict__ cols,
                                             const int* __restrict__ cnt,
                                             int e, int e1, int l, float& ax, float& ay) {
    for (; e + U <= e1; e += U) {
        int j[U];
#pragma unroll
        for (int u = 0; u < U; ++u) j[u] = cols[e + u];
        unsigned w[U];
        float dj[U];
#pragma unroll
        for (int u = 0; u < U; ++u) {
            w[u] = *(const unsigned*)&hs[(size_t)j[u] * 128 + 2 * l];
            dj[u] = dinv_of(cnt[j[u]]);
        }
#pragma unroll
        for (int u = 0; u < U; ++u) {
            ax = fmaf(dj[u], bf2f((ushort)(w[u] & 0xffff)), ax);
            ay = fmaf(dj[u], bf2f((ushort)(w[u] >> 16)), ay);
        }
    }
    return e;
}

template <int U>
__device__ __forceinline__ int gather_tier(const ushort* __restrict__ hs,
                                           const ushort* __restrict__ cols,
                                           int e, int e1, int l, float& ax, float& ay) {
    for (; e + U <= e1; e += U) {
        unsigned w[U];
#pragma unroll
        for (int u = 0; u < U; ++u)
            w[u] = *(const unsigned*)&hs[(size_t)cols[e + u] * 128 + 2 * l];
#pragma unroll
        for (int u = 0; u < U; ++u) acc_edge(ax, ay, w[u]);
    }
    return e;
}

// ---------------- K2: fused agg1 + gemm2 ----------------

__global__ __launch_bounds__(256) void agg1_gemm2_kernel(
    const ushort* __restrict__ hs, const int* __restrict__ cnt,
    const ushort* __restrict__ pad_col, const float* __restrict__ bias,
    const int* __restrict__ ov_cnt, const int2* __restrict__ ov,
    const ushort* __restrict__ WT2p, ushort* __restrict__ outp) {
    __shared__ ushort h1s[16][136];
    int t = threadIdx.x;
    int wv = t >> 6;
    int l = t & 63;
    // ---- phase 1: gather 4 nodes per wave ----
    for (int k = 0; k < 4; ++k) {
        int r = wv * 4 + k;
        int i = blockIdx.x * 16 + r;
        int deg = cnt[i];
        float d = dinv_of(deg);
        unsigned v0 = *(const unsigned*)&hs[(size_t)i * 128 + 2 * l];
        float ax = d * bf2f((ushort)(v0 & 0xffff));
        float ay = d * bf2f((ushort)(v0 >> 16));
        int n = min(deg, PADW);
        const ushort* cols = pad_col + (size_t)i * PADW;
        int e = 0;
        e = gather_tier_d<16>(hs, cols, cnt, e, n, l, ax, ay);
        e = gather_tier_d<8>(hs, cols, cnt, e, n, l, ax, ay);
        e = gather_tier_d<4>(hs, cols, cnt, e, n, l, ax, ay);
        for (; e < n; ++e) {
            int j = cols[e];
            unsigned w = *(const unsigned*)&hs[(size_t)j * 128 + 2 * l];
            float dj = dinv_of(cnt[j]);
            ax = fmaf(dj, bf2f((ushort)(w & 0xffff)), ax);
            ay = fmaf(dj, bf2f((ushort)(w >> 16)), ay);
        }
        if (deg > PADW) {   // overflow rescue
            int oc = min(*ov_cnt, OVCAP);
            for (int kk = 0; kk < oc; ++kk) {
                int2 pr = ov[kk];
                if (pr.x == i) {
                    unsigned w = *(const unsigned*)&hs[(size_t)pr.y * 128 + 2 * l];
                    float dj = dinv_of(cnt[pr.y]);
                    ax = fmaf(dj, bf2f((ushort)(w & 0xffff)), ax);
                    ay = fmaf(dj, bf2f((ushort)(w >> 16)), ay);
                }
            }
        }
        float ox = fmaxf(fmaf(ax, d, bias[2 * l]), 0.f);
        float oy = fmaxf(fmaf(ay, d, bias[2 * l + 1]), 0.f);
        unsigned o = (unsigned)f2bf(ox) | ((unsigned)f2bf(oy) << 16);
        *(unsigned*)&h1s[r][2 * l] = o;
    }
    __syncthreads();
    // ---- phase 2: 16x128 @ 128x128 MFMA; wave wv owns cols [wv*32, wv*32+32) ----
    f32x4 acc2[2] = {};
#pragma unroll
    for (int ks = 0; ks < 4; ++ks) {
        int row = l & 15;
        bf16x8 a = *(const bf16x8*)&h1s[row][ks * 32 + (l >> 4) * 8];
#pragma unroll
        for (int n = 0; n < 2; ++n) {
            int c = wv * 32 + n * 16 + (l & 15);
            int ci = c >> 3, lr = c & 7;
            int ks64 = ks >> 1;
            int q64 = (ks & 1) * 4 + (l >> 4);
            const bf16x8 b = *(const bf16x8*)&WT2p[(size_t)((ci * 2 + ks64) * 64 + lr * 8 + (q64 ^ lr)) * 8];
            acc2[n] = __builtin_amdgcn_mfma_f32_16x16x32_bf16(a, b, acc2[n], 0, 0, 0);
        }
    }
#pragma unroll
    for (int n = 0; n < 2; ++n) {
        int c = wv * 32 + n * 16 + (l & 15);
#pragma unroll
        for (int reg = 0; reg < 4; ++reg) {
            int r = (l >> 4) * 4 + reg;
            int node = blockIdx.x * 16 + r;
            float dd = dinv_of(cnt[node]);
            outp[(size_t)node * 128 + c] = f2bf(acc2[n][reg] * dd);
        }
    }
}

// ---------------- K3: agg2 + heads ----------------

__global__ void agg2_heads_kernel(const ushort* __restrict__ hs, const int* __restrict__ cnt,
                                  const ushort* __restrict__ pad_col,
                                  const float* __restrict__ bias,
                                  const int* __restrict__ ov_cnt, const int2* __restrict__ ov,
                                  const float* __restrict__ Wi, const float* __restrict__ bi,
                                  const float* __restrict__ Wl, const float* __restrict__ bl,
                                  float* __restrict__ out) {
    int wv = threadIdx.x >> 6;
    int l = threadIdx.x & 63;
    int i = blockIdx.x * 4 + wv;
    unsigned v0 = *(const unsigned*)&hs[(size_t)i * 128 + 2 * l];
    float ax = bf2f((ushort)(v0 & 0xffff));
    float ay = bf2f((ushort)(v0 >> 16));
    int deg = cnt[i];
    int n = min(deg, PADW);
    const ushort* cols = pad_col + (size_t)i * PADW;
    int e = 0;
    e = gather_tier<16>(hs, cols, e, n, l, ax, ay);
    e = gather_tier<8>(hs, cols, e, n, l, ax, ay);
    e = gather_tier<4>(hs, cols, e, n, l, ax, ay);
    for (; e < n; ++e)
        acc_edge(ax, ay, *(const unsigned*)&hs[(size_t)cols[e] * 128 + 2 * l]);
    if (deg > PADW) {
        int oc = min(*ov_cnt, OVCAP);
        for (int k = 0; k < oc; ++k) {
            int2 pr = ov[k];
            if (pr.x == i)
                acc_edge(ax, ay, *(const unsigned*)&hs[(size_t)pr.y * 128 + 2 * l]);
        }
    }
    float d = dinv_of(deg);
    float ox = fmaxf(fmaf(ax, d, bias[2 * l]), 0.f);
    float oy = fmaxf(fmaf(ay, d, bias[2 * l + 1]), 0.f);

    float4 u0 = *(const float4*)&Wi[l * 12];
    float4 u1 = *(const float4*)&Wi[l * 12 + 4];
    float4 u2 = *(const float4*)&Wi[l * 12 + 8];
    float pi[6];
    pi[0] = ox * u0.x + oy * u1.z;
    pi[1] = ox * u0.y + oy * u1.w;
    pi[2] = ox * u0.z + oy * u2.x;
    pi[3] = ox * u0.w + oy * u2.y;
    pi[4] = ox * u1.x + oy * u2.z;
    pi[5] = ox * u1.y + oy * u2.w;
    u0 = *(const float4*)&Wl[l * 12];
    u1 = *(const float4*)&Wl[l * 12 + 4];
    u2 = *(const float4*)&Wl[l * 12 + 8];
    float pl[6];
    pl[0] = ox * u0.x + oy * u1.z;
    pl[1] = ox * u0.y + oy * u1.w;
    pl[2] = ox * u0.z + oy * u2.x;
    pl[3] = ox * u0.w + oy * u2.y;
    pl[4] = ox * u1.x + oy * u2.z;
    pl[5] = ox * u1.y + oy * u2.w;
#pragma unroll
    for (int off = 1; off < 64; off <<= 1) {
#pragma unroll
        for (int c = 0; c < 6; ++c) {
            pi[c] += __shfl_xor(pi[c], off);
            pl[c] += __shfl_xor(pl[c], off);
        }
    }
#pragma unroll
    for (int c = 0; c < 6; ++c) {
        pi[c] += bi[c];
        pl[c] += bl[c];
    }
    float mi = fmaxf(fmaxf(fmaxf(pi[0], pi[1]), fmaxf(pi[2], pi[3])), fmaxf(pi[4], pi[5]));
    float ml = fmaxf(fmaxf(fmaxf(pl[0], pl[1]), fmaxf(pl[2], pl[3])), fmaxf(pl[4], pl[5]));
    float si = 0.f, sl = 0.f;
#pragma unroll
    for (int c = 0; c < 6; ++c) {
        si += expf(pi[c] - mi);
        sl += expf(pl[c] - ml);
    }
    float lsi = mi + logf(si), lsl = ml + logf(sl);
#pragma unroll
    for (int c = 0; c < 6; ++c) {
        if (l == c)     out[(size_t)i * NC + c] = pi[c] - lsi;
        if (l == 6 + c) out[(size_t)NN * NC + (size_t)i * NC + c] = pl[c] - lsl;
    }
}

extern "C" void kernel_launch(void* const* d_in, const int* in_sizes, int n_in,
                              void* d_out, int out_size, void* d_ws, size_t ws_size,
                              hipStream_t stream) {
    const float* x  = (const float*)d_in[0];
    const int*   ei = (const int*)d_in[1];
    const float* W1 = (const float*)d_in[2];
    const float* b1 = (const float*)d_in[3];
    const float* W2 = (const float*)d_in[4];
    const float* b2 = (const float*)d_in[5];
    const float* Wi = (const float*)d_in[6];
    const float* bi = (const float*)d_in[7];
    const float* Wl = (const float*)d_in[8];
    const float* bl = (const float*)d_in[9];
    float* out = (float*)d_out;

    uint8_t* p = (uint8_t*)d_ws;
    auto alloc = [&](size_t bytes) {
        void* r = (void*)p;
        p += (bytes + 255) / 256 * 256;
        return r;
    };
    int* cnt        = (int*)alloc((NN + 68) * sizeof(int));   // cnt + ov_cnt at [NN]
    ushort* pad_col = (ushort*)alloc((size_t)NN * PADW * sizeof(ushort));
    int2* ov        = (int2*)alloc((size_t)OVCAP * sizeof(int2));
    ushort* WT1p    = (ushort*)alloc((size_t)KD * HIDD * sizeof(ushort));
    ushort* WT2p    = (ushort*)alloc((size_t)HIDD * HIDD * sizeof(ushort));
    ushort* bufA    = (ushort*)alloc((size_t)NN * HIDD * sizeof(ushort));  // hs1
    ushort* bufC    = (ushort*)alloc((size_t)NN * HIDD * sizeof(ushort));  // hs2
    int* ov_cnt = cnt + NN;

    const int FB = (NE + 511) / 512;       // 1563 fill blocks
    const int PB = 56;                     // pack blocks
    const int NZ4 = (NN + 64) / 4 + 1;
    const int ZB = (NZ4 + 255) / 256;      // 49 zero blocks
    const int GB = (NN + 63) / 64;         // 782 gemm blocks

    // K0: pack weights + zero cnt/ov_cnt
    pack_zero_kernel<<<PB + ZB, 256, 0, stream>>>(cnt, W1, W2, WT1p, WT2p);
    // K1: gemm1 (long blocks first) || single-pass padded fill
    gemm1_fill_kernel<<<GB + FB, 256, 0, stream>>>(x, WT1p, bufA, NN,
                                                   ei, cnt, pad_col, ov_cnt, ov);
    // K2: fused agg1 + gemm2 -> hs2
    agg1_gemm2_kernel<<<NN / 16, 256, 0, stream>>>(bufA, cnt, pad_col, b1, ov_cnt, ov,
                                                   WT2p, bufC);
    // K3: agg2 + heads
    agg2_heads_kernel<<<NN / 4, 256, 0, stream>>>(bufC, cnt, pad_col, b2, ov_cnt, ov,
                                                  Wi, bi, Wl, bl, out);
}